// Round 16
// baseline (79.317 us; speedup 1.0000x reference)
//
#include <hip/hip_runtime.h>
#include <math.h>

// HoltWintersDecomposition: x (8192, 2048) f32, sequential per-row recurrence.
// r16 = r15 + ONE-RCP serial chain (the key algebraic transform):
//   Carry v = rcp(s_e) as a PRODUCT: s_e = D/l_e with D = fma(cs, l_e, g*x),
//   so rcp(s_e) = l_e * rcp(D). Serial path per step becomes
//     lte = fma(ax, v, cl) -> D = fma(cs, lte, gx) -> u = rcp(D) -> v' = lte*u
//   i.e. fma+fma+rcp+mul (~36cy, ONE rcp) instead of rcp+fma+rcp+fma (~58cy).
//   Off-path: z = rcp(lte) (parallel with u), ste = D*z, y = (x*z)*v'
//   (y-form validated r12/r15: y = x*rcp(l+e)*rcp(s+e), absmax 16384).
//   cl = fma(oma, lpe, EPS*alpha), cs = fma(omg, spe, EPS*gamma) off-chain
//   (r13-validated primed-state folding). Algebraically identical to reference.
// Producer step ~40cy -> chain ~35us; consumer now binds -> TWO consumer waves
// (r14 split, neutral then, necessary now).
// Structure: 256 blocks x 32 rows; wave0 producer (32 lanes, full-tile x
// register prefetch, 1-tile distance covers barrier vmcnt drain); waves 1-2
// consumers (transposed full-line stores, half tile each); 1 barrier/tile.
// Lessons: r12 never shrink producer active lanes; r9 producer global loads
// need >= 1-tile distance; r6 parallel-in-time mathematically broken (s~20*EPS).

constexpr int   T    = 2048;
constexpr int   B    = 8192;
constexpr int   RPB  = 32;        // rows per block
constexpr int   TT   = 64;        // steps per tile
constexpr int   NTI  = T / TT;    // 32 tiles
constexpr int   LSX  = 68;        // LDS stride words: 272B rows, 16B-aligned
constexpr float EPS  = 1e-8f;

__global__ __launch_bounds__(192, 1)
void hw_kernel(const float* __restrict__ x,
               const float* __restrict__ pla,
               const float* __restrict__ plg,
               float* __restrict__ out)
{
    __shared__ alignas(16) float LT[2][RPB][LSX];
    __shared__ alignas(16) float ST[2][RPB][LSX];
    __shared__ alignas(16) float YT[2][RPB][LSX];

    const int tid  = threadIdx.x;
    const int wid  = tid >> 6;        // 0 = producer, 1..2 = consumers
    const int lane = tid & 63;
    const int row0 = blockIdx.x * RPB;

    const float alpha = 1.0f / (1.0f + expf(-pla[0]));
    const float gamma = 1.0f / (1.0f + expf(-plg[0]));
    const float oma = 1.0f - alpha, omg = 1.0f - gamma;
    const float EPSa = EPS * alpha;   // folds +EPS into the l fma constant
    const float EPSg = EPS * gamma;   // folds +EPS into the s fma constant

    float* __restrict__ lout = out;
    float* __restrict__ sout = out + (size_t)B * T;
    float* __restrict__ yout = out + (size_t)2 * B * T;

    // store-phase lane mapping (all waves use it in the epilogue)
    const int cr = lane >> 4;          // 0..3
    const int cc = (lane & 15) << 2;   // 0,4,...,60

    auto store_tile = [&](int m, int itlo, int ithi) {
        const int bsel = m & 1;
        const int t0 = m * TT;
        for (int it = itlo; it < ithi; ++it) {
            const int r = 4 * it + cr;
            const size_t g = (size_t)(row0 + r) * T + t0 + cc;
            const float4 vl = *reinterpret_cast<const float4*>(&LT[bsel][r][cc]);
            const float4 vs = *reinterpret_cast<const float4*>(&ST[bsel][r][cc]);
            const float4 vy = *reinterpret_cast<const float4*>(&YT[bsel][r][cc]);
            *reinterpret_cast<float4*>(&lout[g]) = vl;
            *reinterpret_cast<float4*>(&sout[g]) = vs;
            *reinterpret_cast<float4*>(&yout[g]) = vy;
        }
    };

    if (wid == 0) {
        // ================= producer =================
        const bool act = lane < RPB;
        const float* __restrict__ xrow = x + (size_t)(row0 + (act ? lane : 0)) * T;

        float lpe = 0.0f, spe = 1.0f;   // primed state: l+EPS, s+EPS
        float v   = 1.0f;               // v = rcp(spe), carried as product lte*u
        float4 XA[16], XB[16];

        auto loadX = [&](float4* Xb, int k) {
            const float* p = xrow + k * TT;
            #pragma unroll
            for (int i = 0; i < 16; ++i)
                Xb[i] = *reinterpret_cast<const float4*>(p + 4 * i);
        };

        // ONE-rcp chain: lte -> D -> u=rcp(D) -> v'=lte*u.  z=rcp(lte) parallel.
        auto do_step = [&](float xt, float& lo, float& so, float& yo) {
            const float axt = alpha * xt;                       // off-chain
            const float gxt = gamma * xt;                       // off-chain
            const float cl  = __builtin_fmaf(oma, lpe, EPSa);   // off-chain
            const float cs  = __builtin_fmaf(omg, spe, EPSg);   // off-chain
            const float lte = __builtin_fmaf(axt, v, cl);       // chain (= l_t+EPS)
            const float D   = __builtin_fmaf(cs, lte, gxt);     // chain (= ste*lte)
            const float u   = __builtin_amdgcn_rcpf(D);         // chain (the one rcp)
            const float z   = __builtin_amdgcn_rcpf(lte);       // parallel branch
            const float ste = D * z;                            // (= s_t+EPS)
            const float vn  = lte * u;                          // chain (= rcp(ste))
            yo = (xt * z) * vn;                                 // y = x*rl*rs
            lo = lte; so = ste;                                 // primed store
            lpe = lte; spe = ste; v = vn;
        };

        auto compute_tile = [&](const float4* Xb, int k, bool first) {
            const int bsel = k & 1;
            #pragma unroll
            for (int g = 0; g < 16; ++g) {
                const float4 xv = Xb[g];
                float4 lv, sv, yv;
                if (first && g == 0) {
                    // t == 0: l0 = x0, s0 = 1, y0 = x0/(x0 + eps)
                    lpe = xv.x + EPS; spe = 1.0f + EPS;
                    v   = __builtin_amdgcn_rcpf(spe);
                    const float z0 = __builtin_amdgcn_rcpf(lpe);
                    lv.x = xv.x; sv.x = 1.0f;
                    yv.x = xv.x * z0;
                    do_step(xv.y, lv.y, sv.y, yv.y);
                    do_step(xv.z, lv.z, sv.z, yv.z);
                    do_step(xv.w, lv.w, sv.w, yv.w);
                } else {
                    do_step(xv.x, lv.x, sv.x, yv.x);
                    do_step(xv.y, lv.y, sv.y, yv.y);
                    do_step(xv.z, lv.z, sv.z, yv.z);
                    do_step(xv.w, lv.w, sv.w, yv.w);
                }
                *reinterpret_cast<float4*>(&LT[bsel][lane][4 * g]) = lv;
                *reinterpret_cast<float4*>(&ST[bsel][lane][4 * g]) = sv;
                *reinterpret_cast<float4*>(&YT[bsel][lane][4 * g]) = yv;
            }
        };

        if (act) { loadX(XA, 0); loadX(XB, 1); }
        if (act) compute_tile(XA, 0, true);     // one-time vmcnt wait on XA
        __syncthreads();

        #pragma unroll 1
        for (int k = 1; k < NTI - 1; k += 2) {
            if (act) { loadX(XA, k + 1); compute_tile(XB, k, false); }
            __syncthreads();
            if (act) { loadX(XB, k + 2); compute_tile(XA, k + 1, false); }
            __syncthreads();
        }
        if (act) compute_tile(XB, NTI - 1, false);
        __syncthreads();
    } else {
        // ================= consumers: stores only, half tile each =========
        const int lo = (wid - 1) * 4;            // wave1: 0..3, wave2: 4..7
        #pragma unroll 1
        for (int k = 0; k < NTI; ++k) {
            if (k > 0) store_tile(k - 1, lo, lo + 4);
            __syncthreads();
        }
    }

    // epilogue: tile 31 (buffer 1), all three waves split the 8 store groups
    {
        const int lo = (wid == 0) ? 0 : (wid == 1) ? 2 : 5;
        const int hi = (wid == 0) ? 2 : (wid == 1) ? 5 : 8;
        store_tile(NTI - 1, lo, hi);
    }
}

extern "C" void kernel_launch(void* const* d_in, const int* in_sizes, int n_in,
                              void* d_out, int out_size, void* d_ws, size_t ws_size,
                              hipStream_t stream) {
    const float* x   = (const float*)d_in[0];
    const float* pla = (const float*)d_in[1];
    const float* plg = (const float*)d_in[2];
    float* out = (float*)d_out;

    dim3 grid(B / RPB);    // 256 blocks -> one producer + 2 consumers per CU
    dim3 block(192);       // wave0 producer, waves 1-2 consumers
    hw_kernel<<<grid, block, 0, stream>>>(x, pla, plg, out);
}